// Round 1
// baseline (1426.640 us; speedup 1.0000x reference)
//
#include <hip/hip_runtime.h>
#include <math.h>

#define BB 4
#define CC 64
#define HH 96
#define WW 96
#define PP (HH*WW)
#define NHD 4

// ---------------- xp = channel-shifted x ----------------
__global__ __launch_bounds__(256) void k_xp(const float* __restrict__ x, float* __restrict__ xp) {
  int idx = blockIdx.x*256 + threadIdx.x;
  const int total = BB*CC*PP;
  if (idx >= total) return;
  int p = idx % PP; int bc = idx / PP;
  int c = bc % CC;  int b = bc / CC;
  int cs = (c == CC-1) ? c : c+1;
  xp[idx] = x[((size_t)b*CC + cs)*PP + p];
}

// ---------------- avg pool by r ----------------
__global__ __launch_bounds__(256) void k_avgpool(const float* __restrict__ in, float* __restrict__ out,
                                                 int r, int Hs, int Ws) {
  int P = Hs*Ws;
  int total = BB*CC*P;
  int idx = blockIdx.x*256 + threadIdx.x;
  if (idx >= total) return;
  int p = idx % P; int bc = idx / P;
  int y = p / Ws, x = p % Ws;
  int Win = Ws*r;
  const float* ib = in + (size_t)bc*(Hs*r)*(Ws*r);
  float s = 0.f;
  for (int dy=0; dy<r; dy++)
    for (int dx=0; dx<r; dx++)
      s += ib[(y*r+dy)*Win + (x*r+dx)];
  out[idx] = s / (float)(r*r);
}

// ---------------- 1x1 conv (einsum bcp,oc->bop), 16 outputs per thread ----------------
__global__ __launch_bounds__(256) void k_conv1x1(const float* __restrict__ in, const float* __restrict__ w,
                                                 const float* __restrict__ bias, float* __restrict__ out,
                                                 int Cin, int Cout, int P, int wstride, int woff, int accumulate) {
  __shared__ float wl[1024];       // [c][i] transposed, Cin<=64
  int tid = threadIdx.x;
  int obase = blockIdx.y*16;
  for (int t = tid; t < Cin*16; t += 256) {
    int c = t >> 4, i = t & 15;
    wl[t] = w[(size_t)(obase+i)*wstride + woff + c];
  }
  __syncthreads();
  int p = blockIdx.x*256 + tid;
  if (p >= P) return;
  int b = blockIdx.z;
  const float* inb = in + (size_t)b*Cin*P + p;
  float acc[16];
  #pragma unroll
  for (int i=0;i<16;i++) acc[i]=0.f;
  for (int c=0; c<Cin; c++) {
    float v = inb[(size_t)c*P];
    const float* wr = &wl[c*16];
    #pragma unroll
    for (int i=0;i<16;i++) acc[i] = fmaf(v, wr[i], acc[i]);
  }
  float* outb = out + (size_t)b*Cout*P + (size_t)obase*P + p;
  if (accumulate) {
    #pragma unroll
    for (int i=0;i<16;i++) outb[(size_t)i*P] += acc[i];
  } else {
    #pragma unroll
    for (int i=0;i<16;i++) outb[(size_t)i*P] = acc[i] + bias[obase+i];
  }
}

// ---------------- depthwise 3x3 dilated-2 conv, pad 2 ----------------
__global__ __launch_bounds__(256) void k_dwconv(const float* __restrict__ in, const float* __restrict__ w,
                                                const float* __restrict__ bias, float* __restrict__ out,
                                                int Cn, int Hs, int Ws) {
  int P = Hs*Ws;
  int total = BB*Cn*P;
  int idx = blockIdx.x*256 + threadIdx.x;
  if (idx >= total) return;
  int p = idx % P; int bc = idx / P;
  int ch = bc % Cn;
  int y = p / Ws, x = p % Ws;
  const float* wc = w + ch*9;
  const float* inp = in + (size_t)bc*P;
  float acc = bias[ch];
  #pragma unroll
  for (int ky=0; ky<3; ky++) {
    int yy = y + 2*(ky-1);
    if (yy < 0 || yy >= Hs) continue;
    #pragma unroll
    for (int kx=0; kx<3; kx++) {
      int xx = x + 2*(kx-1);
      if (xx < 0 || xx >= Ws) continue;
      acc = fmaf(inp[yy*Ws+xx], wc[ky*3+kx], acc);
    }
  }
  out[idx] = acc;
}

// ---------------- row inverse norms for q (ch 0..63) and k (ch 64..127) ----------------
__global__ __launch_bounds__(256) void k_rownorm(const float* __restrict__ qkv, float* __restrict__ inv, int P) {
  int row = blockIdx.x;              // [0, BB*128)
  int b = row >> 7; int ch = row & 127;
  const float* src = qkv + ((size_t)b*192 + ch)*P;
  float s = 0.f;
  for (int i = threadIdx.x; i < P; i += 256) { float v = src[i]; s += v*v; }
  __shared__ float red[256];
  red[threadIdx.x] = s; __syncthreads();
  for (int st=128; st>0; st>>=1) { if (threadIdx.x < st) red[threadIdx.x] += red[threadIdx.x+st]; __syncthreads(); }
  if (threadIdx.x == 0) inv[row] = 1.0f / fmaxf(sqrtf(red[0]), 1e-12f);
}

// ---------------- gram partials: 4 n-slices per (b,h) ----------------
__global__ __launch_bounds__(256) void k_gram_partial(const float* __restrict__ qkv, float* __restrict__ partials, int P) {
  int bh = blockIdx.x >> 2; int kk = blockIdx.x & 3;
  int b = bh >> 2, h = bh & 3;
  int ci = threadIdx.x >> 4, cj = threadIdx.x & 15;
  __shared__ float qs[16][132], ks[16][132];
  float acc = 0.f;
  for (int n0 = kk*128; n0 < P; n0 += 512) {
    int nrem = P - n0; if (nrem > 128) nrem = 128;
    for (int t = threadIdx.x; t < 2048; t += 256) {
      int r = t >> 7, cc = t & 127;
      float qv = 0.f, kv = 0.f;
      if (cc < nrem) {
        qv = qkv[((size_t)b*192 +      h*16 + r)*P + n0 + cc];
        kv = qkv[((size_t)b*192 + 64 + h*16 + r)*P + n0 + cc];
      }
      qs[r][cc] = qv; ks[r][cc] = kv;
    }
    __syncthreads();
    #pragma unroll 4
    for (int n=0; n<128; n++) acc = fmaf(qs[ci][n], ks[cj][n], acc);
    __syncthreads();
  }
  partials[blockIdx.x*256 + threadIdx.x] = acc;
}

// ---------------- combine partials, normalize, temp-scale, softmax over cj ----------------
__global__ __launch_bounds__(256) void k_softmax16(const float* __restrict__ partials, const float* __restrict__ invn,
                                                   const float* __restrict__ temp, float* __restrict__ attn, int layer) {
  int bh = blockIdx.x; int b = bh >> 2, h = bh & 3;
  int ci = threadIdx.x >> 4, cj = threadIdx.x & 15;
  float raw = 0.f;
  for (int kk=0; kk<4; kk++) raw += partials[(bh*4+kk)*256 + threadIdx.x];
  raw *= invn[b*128 + h*16 + ci] * invn[b*128 + 64 + h*16 + cj] * temp[layer*4 + h];
  __shared__ float m[256];
  m[threadIdx.x] = raw; __syncthreads();
  float mx = -1e30f;
  for (int j=0;j<16;j++) mx = fmaxf(mx, m[ci*16+j]);
  float e = expf(raw - mx);
  __shared__ float ex[256];
  ex[threadIdx.x] = e; __syncthreads();
  float ssum = 0.f;
  for (int j=0;j<16;j++) ssum += ex[ci*16+j];
  attn[bh*256 + threadIdx.x] = e / ssum;
}

// ---------------- out = attn @ v ----------------
__global__ __launch_bounds__(256) void k_attnv(const float* __restrict__ qkv, const float* __restrict__ attn,
                                               float* __restrict__ out, int P) {
  int p = blockIdx.x*256 + threadIdx.x;
  if (p >= P) return;
  int c = blockIdx.y; int b = blockIdx.z;
  int h = c >> 4, ci = c & 15;
  const float* arow = attn + ((b*4 + h)*16 + ci)*16;
  const float* vb = qkv + ((size_t)b*192 + 128 + h*16)*P + p;
  float acc = 0.f;
  #pragma unroll
  for (int j=0;j<16;j++) acc = fmaf(arow[j], vb[(size_t)j*P], acc);
  out[((size_t)b*64 + c)*P + p] = acc;
}

// ---------------- bilinear upsample (JAX half-pixel, clamp == boundary renorm) ----------------
__global__ __launch_bounds__(256) void k_upsample(const float* __restrict__ in, float* __restrict__ out, int Hs, int Ws) {
  int idx = blockIdx.x*256 + threadIdx.x;
  const int total = BB*CC*PP;
  if (idx >= total) return;
  int p = idx % PP; int bc = idx / PP;
  int y = p / WW, x = p % WW;
  float sy = (y + 0.5f) * ((float)Hs / (float)HH) - 0.5f;
  float sx = (x + 0.5f) * ((float)Ws / (float)WW) - 0.5f;
  int y0 = (int)floorf(sy), x0 = (int)floorf(sx);
  float fy = sy - y0, fx = sx - x0;
  int y1 = y0 + 1, x1 = x0 + 1;
  y0 = y0 < 0 ? 0 : (y0 >= Hs ? Hs-1 : y0);
  y1 = y1 < 0 ? 0 : (y1 >= Hs ? Hs-1 : y1);
  x0 = x0 < 0 ? 0 : (x0 >= Ws ? Ws-1 : x0);
  x1 = x1 < 0 ? 0 : (x1 >= Ws ? Ws-1 : x1);
  const float* ib = in + (size_t)bc*Hs*Ws;
  float v = (1.f-fy)*((1.f-fx)*ib[y0*Ws+x0] + fx*ib[y0*Ws+x1])
          +      fy *((1.f-fx)*ib[y1*Ws+x0] + fx*ib[y1*Ws+x1]);
  out[idx] = v;
}

// ---------------- fused per-pixel Mamba: 8 sequences per block, 32 threads/seq ----------------
__global__ __launch_bounds__(256) void k_mamba(
    const float* __restrict__ xre, const float* __restrict__ in_w,
    const float* __restrict__ cw, const float* __restrict__ cb,
    const float* __restrict__ xpw, const float* __restrict__ dtw_,
    const float* __restrict__ dtb_, const float* __restrict__ Alog,
    const float* __restrict__ Dp, const float* __restrict__ ow,
    float* __restrict__ xr) {
  int sl = threadIdx.x >> 5;
  int d  = threadIdx.x & 31;
  int nb = blockIdx.x*8;
  int b = nb / PP, p0 = nb % PP;
  const float* src = xre + (size_t)b*CC*PP + p0;

  __shared__ float xs[8][64];
  __shared__ float u_s[8][4][32];     // u, later reused for y
  __shared__ float dtr[8][4];
  __shared__ float Bs[8][4][16];
  __shared__ float Cs[8][4][16];
  __shared__ float os[8][64];

  for (int t = threadIdx.x; t < 512; t += 256) {
    int c = t >> 3, off = t & 7;
    xs[off][c] = src[(size_t)c*PP + off];
  }
  __syncthreads();

  // xz = xs @ in_w.T  (own d)
  float xi[4], zz[4];
  #pragma unroll
  for (int t=0;t<4;t++) {
    float a = 0.f, b2 = 0.f;
    #pragma unroll
    for (int g=0; g<16; g++) {
      float v = xs[sl][t*16+g];
      a  = fmaf(v, in_w[d*16+g], a);
      b2 = fmaf(v, in_w[(32+d)*16+g], b2);
    }
    xi[t] = a; zz[t] = b2;
  }
  // causal depthwise conv over L + silu
  float u[4];
  #pragma unroll
  for (int t=0;t<4;t++) {
    float s = cb[d];
    #pragma unroll
    for (int k=0;k<4;k++) {
      int ti = t-3+k;
      if (ti >= 0) s = fmaf(xi[ti], cw[d*4+k], s);
    }
    u[t] = s / (1.f + expf(-s));
    u_s[sl][t][d] = u[t];
  }
  __syncthreads();
  // xdbl = u @ xp_w.T : thread d does row r=d; thread 0 also r=32
  #pragma unroll
  for (int t=0;t<4;t++) {
    float s = 0.f;
    #pragma unroll
    for (int dd=0; dd<32; dd++) s = fmaf(u_s[sl][t][dd], xpw[d*32+dd], s);
    if (d == 0) dtr[sl][t] = s;
    else if (d <= 16) Bs[sl][t][d-1] = s;
    else Cs[sl][t][d-17] = s;
  }
  if (d == 0) {
    #pragma unroll
    for (int t=0;t<4;t++) {
      float s = 0.f;
      #pragma unroll
      for (int dd=0; dd<32; dd++) s = fmaf(u_s[sl][t][dd], xpw[32*32+dd], s);
      Cs[sl][t][15] = s;
    }
  }
  __syncthreads();

  // selective scan (state in registers)
  float hst[16];
  #pragma unroll
  for (int s2=0;s2<16;s2++) hst[s2] = 0.f;
  float Av[16];
  #pragma unroll
  for (int s2=0;s2<16;s2++) Av[s2] = -expf(Alog[d*16+s2]);
  float dtw = dtw_[d], dtb = dtb_[d], Dd = Dp[d];
  #pragma unroll
  for (int t=0;t<4;t++) {
    float dv = dtr[sl][t]*dtw + dtb;
    dv = (dv > 20.f) ? dv : log1pf(expf(dv));
    float y = 0.f;
    #pragma unroll
    for (int s2=0;s2<16;s2++) {
      hst[s2] = expf(dv*Av[s2])*hst[s2] + dv*Bs[sl][t][s2]*u[t];
      y = fmaf(hst[s2], Cs[sl][t][s2], y);
    }
    y += u[t]*Dd;
    y *= zz[t] / (1.f + expf(-zz[t]));
    u_s[sl][t][d] = y;                 // reuse as y storage
  }
  __syncthreads();
  // out = y @ out_w.T : each thread 2 of 64 outputs
  {
    int g = d & 15;
    int t0 = d >> 4;
    #pragma unroll
    for (int rep=0; rep<2; rep++) {
      int t = t0 + 2*rep;
      float s = 0.f;
      #pragma unroll
      for (int dd=0; dd<32; dd++) s = fmaf(u_s[sl][t][dd], ow[g*32+dd], s);
      os[sl][t*16+g] = s;
    }
  }
  __syncthreads();
  float* dst = xr + (size_t)b*CC*PP + p0;
  for (int t = threadIdx.x; t < 512; t += 256) {
    int c = t >> 3, off = t & 7;
    dst[(size_t)c*PP + off] = os[off][c];
  }
}

// ---------------- group-norm stats (16 blocks) ----------------
__global__ __launch_bounds__(256) void k_gnstats(const float* __restrict__ xr, float* __restrict__ stats) {
  int bg = blockIdx.x; int b = bg >> 2; int g = bg & 3;
  const float* src = xr + (size_t)b*CC*PP + (size_t)g*16*PP;
  const int Ntot = 16*PP;
  float s = 0.f, ss = 0.f;
  for (int i = threadIdx.x; i < Ntot; i += 256) { float v = src[i]; s += v; ss += v*v; }
  __shared__ float r1[256], r2[256];
  r1[threadIdx.x] = s; r2[threadIdx.x] = ss; __syncthreads();
  for (int st=128; st>0; st>>=1) {
    if (threadIdx.x < st) { r1[threadIdx.x] += r1[threadIdx.x+st]; r2[threadIdx.x] += r2[threadIdx.x+st]; }
    __syncthreads();
  }
  if (threadIdx.x == 0) {
    float mu = r1[0] / (float)Ntot;
    stats[bg*2] = mu;
    stats[bg*2+1] = r2[0] / (float)Ntot - mu*mu;
  }
}

// ---------------- normalize + affine + silu + residual ----------------
__global__ __launch_bounds__(256) void k_final(const float* __restrict__ xr, const float* __restrict__ x,
                                               const float* __restrict__ stats, const float* __restrict__ gw,
                                               const float* __restrict__ gb, float* __restrict__ out) {
  int idx = blockIdx.x*256 + threadIdx.x;
  const int total = BB*CC*PP;
  if (idx >= total) return;
  int bc = idx / PP;
  int c = bc % CC; int b = bc / CC;
  int g = c >> 4;
  float mu = stats[(b*4+g)*2], var = stats[(b*4+g)*2+1];
  float v = (xr[idx] - mu) * rsqrtf(var + 1e-5f) * gw[c] + gb[c];
  v = v / (1.f + expf(-v));
  out[idx] = v + x[idx];
}

extern "C" void kernel_launch(void* const* d_in, const int* in_sizes, int n_in,
                              void* d_out, int out_size, void* d_ws, size_t ws_size,
                              hipStream_t stream) {
  const float* x      = (const float*)d_in[0];
  const float* qkv_w  = (const float*)d_in[1];
  const float* qkv_b  = (const float*)d_in[2];
  const float* dw_w   = (const float*)d_in[3];
  const float* dw_b   = (const float*)d_in[4];
  const float* po_w   = (const float*)d_in[5];
  const float* po_b   = (const float*)d_in[6];
  const float* temp   = (const float*)d_in[7];
  const float* prca_w = (const float*)d_in[8];
  const float* prca_b = (const float*)d_in[9];
  const float* m_in_w = (const float*)d_in[10];
  const float* m_cw   = (const float*)d_in[11];
  const float* m_cb   = (const float*)d_in[12];
  const float* m_xpw  = (const float*)d_in[13];
  const float* m_dtw  = (const float*)d_in[14];
  const float* m_dtb  = (const float*)d_in[15];
  const float* m_Alog = (const float*)d_in[16];
  const float* m_D    = (const float*)d_in[17];
  const float* m_ow   = (const float*)d_in[18];
  const float* gn_w   = (const float*)d_in[19];
  const float* gn_b   = (const float*)d_in[20];
  float* out = (float*)d_out;

  const size_t SZ64  = (size_t)BB*CC*PP;    // 2,359,296
  const size_t SZ192 = (size_t)BB*192*PP;   // 7,077,888
  size_t need = (4*SZ64 + 2*SZ192 + 512 + 4096 + 16384 + 32) * sizeof(float);
  if (ws_size < need) return;  // fail loudly (output untouched)

  float* ws       = (float*)d_ws;
  float* xp       = ws;
  float* scaleIn  = xp + SZ64;
  float* obuf     = scaleIn + SZ64;
  float* qkv_a    = obuf + SZ64;
  float* qkv_b2   = qkv_a + SZ192;
  float* prca     = qkv_b2 + SZ192;
  float* norms    = prca + SZ64;
  float* attn     = norms + 512;
  float* partials = attn + 4096;
  float* stats    = partials + 16384;

  dim3 thr(256);

  k_xp<<<dim3((SZ64+255)/256), thr, 0, stream>>>(x, xp);

  for (int s = 0; s < 3; s++) {
    int dim = 96 >> s; int P = dim*dim;
    const float* in_ptr;
    if (s == 0) in_ptr = xp;
    else {
      int r = 1 << s;
      k_avgpool<<<dim3((BB*CC*P+255)/256), thr, 0, stream>>>(xp, scaleIn, r, dim, dim);
      in_ptr = scaleIn;
    }
    for (int j = 0; j < 3; j++) {
      int i = 3*s + j;
      k_conv1x1<<<dim3((P+255)/256, 12, BB), thr, 0, stream>>>(
          in_ptr, qkv_w + (size_t)i*192*64, qkv_b + i*192, qkv_a, 64, 192, P, 64, 0, 0);
      k_dwconv<<<dim3((BB*192*P+255)/256), thr, 0, stream>>>(
          qkv_a, dw_w + (size_t)i*192*9, dw_b + i*192, qkv_b2, 192, dim, dim);
      k_rownorm<<<dim3(BB*128), thr, 0, stream>>>(qkv_b2, norms, P);
      k_gram_partial<<<dim3(BB*NHD*4), thr, 0, stream>>>(qkv_b2, partials, P);
      k_softmax16<<<dim3(BB*NHD), thr, 0, stream>>>(partials, norms, temp, attn, i);
      k_attnv<<<dim3((P+255)/256, 64, BB), thr, 0, stream>>>(qkv_b2, attn, qkv_a, P);
      k_conv1x1<<<dim3((P+255)/256, 4, BB), thr, 0, stream>>>(
          qkv_a, po_w + (size_t)i*64*64, po_b + i*64, obuf, 64, 64, P, 64, 0, 0);
      in_ptr = obuf;
    }
    const float* res = in_ptr;
    if (s > 0) {
      k_upsample<<<dim3((SZ64+255)/256), thr, 0, stream>>>(res, qkv_b2, dim, dim);
      res = qkv_b2;
    }
    k_conv1x1<<<dim3((PP+255)/256, 4, BB), thr, 0, stream>>>(
        res, prca_w, prca_b, prca, 64, 64, PP, 192, s*64, (s == 0) ? 0 : 1);
  }

  float* xr = qkv_a;   // reuse
  k_mamba<<<dim3(BB*PP/8), thr, 0, stream>>>(
      prca, m_in_w, m_cw, m_cb, m_xpw, m_dtw, m_dtb, m_Alog, m_D, m_ow, xr);
  k_gnstats<<<dim3(16), thr, 0, stream>>>(xr, stats);
  k_final<<<dim3((SZ64+255)/256), thr, 0, stream>>>(xr, x, stats, gn_w, gn_b, out);
}